// Round 2
// baseline (275.202 us; speedup 1.0000x reference)
//
#include <hip/hip_runtime.h>
#include <math.h>

#define B_N     16384
#define D_N     512
#define NPAIR   8192
#define CON_BLOCKS 2048          // NPAIR / 4 waves
#define COX_BLOCKS 256           // 64 i's per block
#define COX_THREADS 512          // 8 waves, each takes 1/8 of the j-range
#define TILE_J  4096             // j-tile staged in LDS (16 B/entry = 64 KB)
#define N_TILE  (B_N / TILE_J)

__device__ __forceinline__ float wave_reduce(float v) {
    #pragma unroll
    for (int m = 32; m >= 1; m >>= 1) v += __shfl_xor(v, m, 64);
    return v;
}

__device__ __forceinline__ float dot4(float4 a, float4 b) {
    return a.x*b.x + a.y*b.y + a.z*b.z + a.w*b.w;
}

// ---------------------------------------------------------------------------
// Fused Cox + NLL, brute force O(B^2) with u64 sort-key compare.
// key_j = (bits(t_j) << 14) | (16383 - j); predicate "j at-or-before i in
// stable argsort(-t)" (j != i)  <=>  key_j > key_i.  Self term e_i added once.
// Grid: 256 blocks x 512 threads. i = blockIdx*64 + lane; wave w covers
// j-subrange w/8 of each 4096-entry LDS tile (broadcast reads, conflict-free).
// Outputs per-block partials (no atomics, no zero-init needed).
// ---------------------------------------------------------------------------
__global__ __launch_bounds__(COX_THREADS) void k_cox_nll(
        const float* __restrict__ hazard,
        const float* __restrict__ score,
        const float* __restrict__ time,
        const int*   __restrict__ event,
        float* __restrict__ partCox,
        float* __restrict__ partNll,
        float* __restrict__ partEv)
{
    __shared__ uint4 tile[TILE_J];          // {key_lo, key_hi, bits(e), 0}

    const int lane = threadIdx.x & 63;
    const int wave = threadIdx.x >> 6;
    const int i    = blockIdx.x * 64 + lane;

    const float ti = time[i];
    const unsigned long long key_i =
        (((unsigned long long)__float_as_uint(ti)) << 14) |
        (unsigned long long)(B_N - 1 - i);

    float cum = 0.f;

    for (int t = 0; t < N_TILE; ++t) {
        __syncthreads();                    // LDS safe to overwrite
        #pragma unroll
        for (int q = threadIdx.x; q < TILE_J; q += COX_THREADS) {
            const int j = t * TILE_J + q;
            const float tj = time[j];
            const float ej = __expf(hazard[j]);
            const unsigned long long kj =
                (((unsigned long long)__float_as_uint(tj)) << 14) |
                (unsigned long long)(B_N - 1 - j);
            tile[q] = make_uint4((unsigned)(kj & 0xffffffffu),
                                 (unsigned)(kj >> 32),
                                 __float_as_uint(ej), 0u);
        }
        __syncthreads();

        const int base = wave * (TILE_J / 8);
        #pragma unroll 8
        for (int q = 0; q < TILE_J / 8; ++q) {
            const uint4 v = tile[base + q];
            const unsigned long long kj =
                (((unsigned long long)v.y) << 32) | v.x;
            if (kj > key_i) cum += __uint_as_float(v.z);
        }
    }

    __syncthreads();
    float* cum_sh = (float*)tile;           // reuse LDS: [8][64]
    cum_sh[wave * 64 + lane] = cum;
    __syncthreads();

    if (wave == 0) {
        float c = 0.f;
        #pragma unroll
        for (int w = 0; w < 8; ++w) c += cum_sh[w * 64 + lane];
        const float hi = hazard[i];
        c += __expf(hi);                    // self term (j == i)
        const int ev = event[i];
        float cox_p = ev ? (hi - logf(c + 1e-6f)) : 0.f;
        float nll_p = score[i * 2 + ev];
        float ev_p  = (float)ev;
        cox_p = wave_reduce(cox_p);
        nll_p = wave_reduce(nll_p);
        ev_p  = wave_reduce(ev_p);
        if (lane == 0) {
            partCox[blockIdx.x] = cox_p;
            partNll[blockIdx.x] = nll_p;
            partEv[blockIdx.x]  = ev_p;
        }
    }
}

// ---------------------------------------------------------------------------
// Contrastive term: one wave per pair, 6 rows x 2KB each, fully coalesced.
// ---------------------------------------------------------------------------
__global__ __launch_bounds__(256) void k_con(const float* __restrict__ rep1,
                                             const float* __restrict__ rep2,
                                             const float* __restrict__ rep3,
                                             const int* __restrict__ x1_idx,
                                             const int* __restrict__ x2_idx,
                                             float* __restrict__ partCon)
{
    __shared__ float wsum[4];
    const int lane = threadIdx.x & 63;
    const int wave = threadIdx.x >> 6;
    const int p = blockIdx.x * 4 + wave;
    const int ia = x1_idx[p];
    const int ib = x2_idx[p];
    const float4* A1 = (const float4*)(rep1 + (size_t)ia * D_N);
    const float4* A2 = (const float4*)(rep2 + (size_t)ia * D_N);
    const float4* A3 = (const float4*)(rep3 + (size_t)ia * D_N);
    const float4* B1 = (const float4*)(rep1 + (size_t)ib * D_N);
    const float4* B2 = (const float4*)(rep2 + (size_t)ib * D_N);
    const float4* B3 = (const float4*)(rep3 + (size_t)ib * D_N);

    float v[15];
    #pragma unroll
    for (int k = 0; k < 15; ++k) v[k] = 0.f;

    #pragma unroll
    for (int r = 0; r < 2; ++r) {
        const int k = lane + r * 64;
        float4 a1 = A1[k], a2 = A2[k], a3 = A3[k];
        float4 b1 = B1[k], b2 = B2[k], b3 = B3[k];
        v[0]  += dot4(a1, a1); v[1]  += dot4(a2, a2); v[2]  += dot4(a3, a3);
        v[3]  += dot4(b1, b1); v[4]  += dot4(b2, b2); v[5]  += dot4(b3, b3);
        v[6]  += dot4(a1, a2); v[7]  += dot4(a1, a3); v[8]  += dot4(a2, a3);
        v[9]  += dot4(b1, b2); v[10] += dot4(b1, b3); v[11] += dot4(b2, b3);
        v[12] += dot4(a1, b1); v[13] += dot4(a2, b2); v[14] += dot4(a3, b3);
    }
    #pragma unroll
    for (int k = 0; k < 15; ++k) v[k] = wave_reduce(v[k]);

    if (lane == 0) {
        float n1a = fmaxf(sqrtf(v[0]), 1e-8f), n2a = fmaxf(sqrtf(v[1]), 1e-8f), n3a = fmaxf(sqrtf(v[2]), 1e-8f);
        float n1b = fmaxf(sqrtf(v[3]), 1e-8f), n2b = fmaxf(sqrtf(v[4]), 1e-8f), n3b = fmaxf(sqrtf(v[5]), 1e-8f);
        float dxx = v[6]/(n1a*n2a) + v[7]/(n1a*n3a) + v[8]/(n2a*n3a);
        float dyy = v[9]/(n1b*n2b) + v[10]/(n1b*n3b) + v[11]/(n2b*n3b);
        float dxy = v[12]/(n1a*n1b) + v[13]/(n2a*n2b) + v[14]/(n3a*n3b);
        float s = 0.2f + dxy - 0.5f*dxx - 0.5f*dyy;
        wsum[wave] = log1pf(expf(s));
    }
    __syncthreads();
    if (threadIdx.x == 0)
        partCon[blockIdx.x] = wsum[0] + wsum[1] + wsum[2] + wsum[3];
}

// ---------------------------------------------------------------------------
// Final reduction of all partials. 1 block x 256 threads.
// ---------------------------------------------------------------------------
__global__ __launch_bounds__(256) void k_final(const float* __restrict__ partCon,
                                               const float* __restrict__ partCox,
                                               const float* __restrict__ partNll,
                                               const float* __restrict__ partEv,
                                               float* __restrict__ out)
{
    __shared__ float sh[4][4];
    const int tid  = threadIdx.x;
    const int lane = tid & 63;
    const int wave = tid >> 6;

    float con = 0.f;
    #pragma unroll
    for (int k = 0; k < CON_BLOCKS / 256; ++k) con += partCon[tid + k * 256];
    float cox = partCox[tid];
    float nll = partNll[tid];
    float ev  = partEv[tid];

    con = wave_reduce(con);
    cox = wave_reduce(cox);
    nll = wave_reduce(nll);
    ev  = wave_reduce(ev);
    if (lane == 0) {
        sh[wave][0] = con; sh[wave][1] = cox; sh[wave][2] = nll; sh[wave][3] = ev;
    }
    __syncthreads();
    if (tid == 0) {
        float C = sh[0][0] + sh[1][0] + sh[2][0] + sh[3][0];
        float X = sh[0][1] + sh[1][1] + sh[2][1] + sh[3][1];
        float N = sh[0][2] + sh[1][2] + sh[2][2] + sh[3][2];
        float E = sh[0][3] + sh[1][3] + sh[2][3] + sh[3][3];
        float nll_t = -N / (float)B_N;
        float cox_t = -X / (E + 1e-6f);
        float con_t = C / (float)NPAIR;
        out[0] = nll_t + cox_t + 0.3f * con_t;
    }
}

extern "C" void kernel_launch(void* const* d_in, const int* in_sizes, int n_in,
                              void* d_out, int out_size, void* d_ws, size_t ws_size,
                              hipStream_t stream)
{
    const float* rep1   = (const float*)d_in[0];
    const float* rep2   = (const float*)d_in[1];
    const float* rep3   = (const float*)d_in[2];
    const float* hazard = (const float*)d_in[3];
    const float* score  = (const float*)d_in[4];
    const float* time_  = (const float*)d_in[5];
    const int*   event  = (const int*)d_in[6];
    const int*   x1     = (const int*)d_in[7];
    const int*   x2     = (const int*)d_in[8];
    float* out = (float*)d_out;

    char* w = (char*)d_ws;
    float* partCon = (float*)(w);                    // 2048 floats
    float* partCox = (float*)(w + 8192);             // 256 floats
    float* partNll = (float*)(w + 9216);             // 256 floats
    float* partEv  = (float*)(w + 10240);            // 256 floats
    // every slot is written by exactly one block -> no zero-init needed

    k_con     <<<CON_BLOCKS, 256, 0, stream>>>(rep1, rep2, rep3, x1, x2, partCon);
    k_cox_nll <<<COX_BLOCKS, COX_THREADS, 0, stream>>>(hazard, score, time_, event,
                                                       partCox, partNll, partEv);
    k_final   <<<1, 256, 0, stream>>>(partCon, partCox, partNll, partEv, out);
}